// Round 7
// baseline (14730.406 us; speedup 1.0000x reference)
//
#include <hip/hip_runtime.h>

#define NPRI 21504
#define BATCH 64
#define KTOP 1024
#define NWORDS ((NPRI + 63) / 64)

typedef unsigned long long u64;
typedef unsigned int u32;

// correctly-rounded f32 exp via f64 libm exp (double-rounding risk ~2^-40, negligible)
__device__ __forceinline__ float crexpf(float x) {
  return (float)exp((double)x);
}

// K1: f32-stepwise softmax[:,1], replicating jax.nn.softmax / np with max-subtraction:
// m = max(c0,c1); e_i = exp32(c_i - m); s = e1 / (e0 + e1). All ops f32 IEEE-CR.
__global__ void k_score(const float* __restrict__ confs, float* __restrict__ sg) {
  int t = blockIdx.x * blockDim.x + threadIdx.x;
  if (t < BATCH * NPRI) {
    float c0 = confs[2 * t];
    float c1 = confs[2 * t + 1];
    float m = fmaxf(c0, c1);
    float e0 = crexpf(c0 - m);     // exp32(0) == 1.0f exactly for the max element
    float e1 = crexpf(c1 - m);
    float den = e0 + e1;
    sg[t] = e1 / den;
  }
}

// K2: per image: top-1024 by repeated argmax on (s32 desc, idx asc) — exactly
// lax.top_k's stable ordering on the f32 scores — then f32-stepwise box decode.
__global__ __launch_bounds__(256) void k_topk(const float* __restrict__ sg,
                                              const float* __restrict__ locs,
                                              const float* __restrict__ priors,
                                              float* __restrict__ boxF,
                                              float* __restrict__ scoreF,
                                              int* __restrict__ validI) {
  const int b = blockIdx.x;
  const int tid = threadIdx.x;
  __shared__ u64 taken[NWORDS];       // 336 words: extracted-index bitmask
  __shared__ float bz[256];
  __shared__ int bi[256];
  __shared__ float topS[KTOP];
  __shared__ int topI[KTOP];
  for (int i = tid; i < NWORDS; i += 256) taken[i] = 0;
  __syncthreads();

  const float* s = sg + (size_t)b * NPRI;
  const float NEG = -__builtin_inff();
  // thread t owns indices n with n % 256 == t (84 each; 21504 = 84*256)
  float myBest = NEG;
  int myIdx = NPRI;
  bool dirty = true;

  for (int r = 0; r < KTOP; r++) {
    if (dirty) {
      myBest = NEG; myIdx = NPRI;
      for (int n = tid; n < NPRI; n += 256) {
        if (!((taken[n >> 6] >> (n & 63)) & 1ULL)) {
          float v = s[n];
          if (v > myBest) { myBest = v; myIdx = n; }  // ascending n: first hit wins ties
        }
      }
      dirty = false;
    }
    bz[tid] = myBest; bi[tid] = myIdx;
    __syncthreads();
    for (int st = 128; st > 0; st >>= 1) {
      if (tid < st) {
        float ov = bz[tid + st]; int oi = bi[tid + st];
        float mv = bz[tid];      int mi = bi[tid];
        if (ov > mv || (ov == mv && oi < mi)) { bz[tid] = ov; bi[tid] = oi; }
      }
      __syncthreads();
    }
    int w = bi[0];
    float ws = bz[0];
    if (tid == 0) {
      topS[r] = ws; topI[r] = w;
      taken[w >> 6] |= (1ULL << (w & 63));
    }
    if ((w & 255) == tid) dirty = true;   // owner of w rescans next round
    __syncthreads();                      // taken update visible; bz/bi reusable
  }

  // decode, f32-stepwise in the reference's association order
  for (int i = tid; i < KTOP; i += 256) {
    float sv = topS[i];
    int idx = topI[i];
    float4 lo = ((const float4*)locs)[(size_t)b * NPRI + idx];
    float4 pr = ((const float4*)priors)[idx];
    float cx = pr.x + (lo.x * 0.1f) * pr.z;   // priors[:,:2] + (loc[:,:2]*VAR0)*priors[:,2:]
    float cy = pr.y + (lo.y * 0.1f) * pr.w;
    float w  = pr.z * crexpf(lo.z * 0.2f);    // priors[:,2:]*exp(loc[:,2:]*VAR1)
    float h  = pr.w * crexpf(lo.w * 0.2f);
    float x1 = cx - w * 0.5f;                 // xy1 = cxy - wh/2
    float y1 = cy - h * 0.5f;
    float x2 = x1 + w;                        // xy2 = xy1 + wh
    float y2 = y1 + h;
    size_t o = (size_t)b * KTOP + i;
    boxF[o * 4 + 0] = x1;
    boxF[o * 4 + 1] = y1;
    boxF[o * 4 + 2] = x2;
    boxF[o * 4 + 3] = y2;
    scoreF[o] = sv;
    validI[o] = (sv > 0.5f) ? 1 : 0;          // valid = top_scores > CONF_THRESH
  }
}

// K3: per image: literal transcription of the reference fori_loop NMS in f32,
// then masked f32 output write.
__global__ __launch_bounds__(256) void k_nms(const float* __restrict__ boxF,
                                             const float* __restrict__ scoreF,
                                             const int* __restrict__ validI,
                                             float* __restrict__ out) {
  const int b = blockIdx.x;
  const int tid = threadIdx.x;
  __shared__ float X1[KTOP], Y1[KTOP], X2[KTOP], Y2[KTOP], AR[KTOP];
  __shared__ unsigned char keep[KTOP];
  const float* bb = boxF + (size_t)b * KTOP * 4;
  for (int i = tid; i < KTOP; i += 256) {
    float x1 = bb[i * 4 + 0], y1 = bb[i * 4 + 1];
    float x2 = bb[i * 4 + 2], y2 = bb[i * 4 + 3];
    X1[i] = x1; Y1[i] = y1; X2[i] = x2; Y2[i] = y2;
    // area = clip(x2-x1,0) * clip(y2-y1,0)
    AR[i] = fmaxf(x2 - x1, 0.0f) * fmaxf(y2 - y1, 0.0f);
    keep[i] = (unsigned char)validI[(size_t)b * KTOP + i];
  }
  __syncthreads();
  for (int i = 0; i < KTOP; i++) {
    if (keep[i]) {          // uniform branch (same LDS value for all threads)
      float x1 = X1[i], y1 = Y1[i], x2 = X2[i], y2 = Y2[i], a = AR[i];
      for (int j = i + 1 + tid; j < KTOP; j += 256) {
        float lx = fmaxf(x1, X1[j]);
        float ly = fmaxf(y1, Y1[j]);
        float rx = fminf(x2, X2[j]);
        float ry = fminf(y2, Y2[j]);
        float iw = fmaxf(rx - lx, 0.0f);
        float ih = fmaxf(ry - ly, 0.0f);
        float inter = iw * ih;
        float uni = (a + AR[j]) - inter;             // area_i + area_j - inter
        float iou = inter / fmaxf(uni, 1e-9f);       // inter / max(union, 1e-9)
        if (iou > 0.4f) keep[j] = 0;                 // NMS_THRESH as f32 (weak scalar)
      }
    }
    __syncthreads();
  }
  const float* sc = scoreF + (size_t)b * KTOP;
  for (int i = tid; i < KTOP; i += 256) {
    float kf = keep[i] ? 1.0f : 0.0f;
    size_t o5 = ((size_t)b * KTOP + i) * 5;
    out[o5 + 0] = X1[i] * kf;
    out[o5 + 1] = Y1[i] * kf;
    out[o5 + 2] = X2[i] * kf;
    out[o5 + 3] = Y2[i] * kf;
    out[o5 + 4] = sc[i] * kf;
    out[(size_t)BATCH * KTOP * 5 + (size_t)b * KTOP + i] = kf;
  }
}

extern "C" void kernel_launch(void* const* d_in, const int* in_sizes, int n_in,
                              void* d_out, int out_size, void* d_ws, size_t ws_size,
                              hipStream_t stream) {
  // Defensive dispatch by element count (locs=B*N*4, confs=B*N*2, priors=N*4)
  const float* locs = nullptr;
  const float* confs = nullptr;
  const float* priors = nullptr;
  for (int i = 0; i < n_in; i++) {
    if (in_sizes[i] == BATCH * NPRI * 4) locs = (const float*)d_in[i];
    else if (in_sizes[i] == BATCH * NPRI * 2) confs = (const float*)d_in[i];
    else if (in_sizes[i] == NPRI * 4) priors = (const float*)d_in[i];
  }
  float* out = (float*)d_out;   // f32: [B,K,5] dets ++ [B,K] keep

  char* ws = (char*)d_ws;
  size_t off = 0;
  float* sg = (float*)(ws + off);        off += (size_t)BATCH * NPRI * 4;       // 5,505,024
  float* boxF = (float*)(ws + off);      off += (size_t)BATCH * KTOP * 4 * 4;   // 1,048,576
  float* scoreF = (float*)(ws + off);    off += (size_t)BATCH * KTOP * 4;       //   262,144
  int* validI = (int*)(ws + off);        off += (size_t)BATCH * KTOP * 4;       //   262,144

  k_score<<<(BATCH * NPRI + 255) / 256, 256, 0, stream>>>(confs, sg);
  k_topk<<<BATCH, 256, 0, stream>>>(sg, locs, priors, boxF, scoreF, validI);
  k_nms<<<BATCH, 256, 0, stream>>>(boxF, scoreF, validI, out);
}

// Round 8
// 488.867 us; speedup vs baseline: 30.1317x; 30.1317x over previous
//
#include <hip/hip_runtime.h>

#define NPRI 21504
#define BATCH 64
#define KTOP 1024
#define NCH 21

typedef unsigned long long u64;
typedef unsigned int u32;

// correctly-rounded f32 exp via f64 libm exp (validated round 7: absmax 3e-8)
__device__ __forceinline__ float crexpf(float x) { return (float)exp((double)x); }

// Key packing: score>0 so f32 bits are order-monotone. NPRI-1-idx < 2^15.
// Descending u64 order == (score desc, idx asc) == lax.top_k stable order.

// K1: fused f32-stepwise softmax score + per-chunk bitonic sort (desc) of u64 keys.
__global__ __launch_bounds__(256) void k_sort(const float* __restrict__ confs,
                                              u64* __restrict__ keyG) {
  const int b = blockIdx.x / NCH;
  const int c = blockIdx.x % NCH;
  __shared__ u64 ks[KTOP];
  const float2* cf = (const float2*)confs + (size_t)b * NPRI + c * KTOP;
  for (int i = threadIdx.x; i < KTOP; i += 256) {
    float2 v = cf[i];
    float m = fmaxf(v.x, v.y);
    float e0 = crexpf(v.x - m);
    float e1 = crexpf(v.y - m);
    float s = e1 / (e0 + e1);          // exact f32 steps (round-7-validated)
    int idx = c * KTOP + i;
    ks[i] = ((u64)__float_as_uint(s) << 15) | (u64)(NPRI - 1 - idx);
  }
  for (int k = 2; k <= KTOP; k <<= 1) {
    for (int j = k >> 1; j > 0; j >>= 1) {
      __syncthreads();
      for (int l = threadIdx.x; l < KTOP; l += 256) {
        int p = l ^ j;
        if (p > l) {
          u64 a = ks[l], q = ks[p];
          bool up = ((l & k) == 0);
          if ((a > q) != up) { ks[l] = q; ks[p] = a; }   // up-block: descending
        }
      }
    }
  }
  __syncthreads();
  u64* dst = keyG + (size_t)b * NPRI + (size_t)c * KTOP;
  for (int i = threadIdx.x; i < KTOP; i += 256) dst[i] = ks[i];
}

// K2: per image: 20 bitonic top-k merges of the 21 sorted runs, then f32 decode.
__global__ __launch_bounds__(256) void k_merge(const u64* __restrict__ keyG,
                                               const float* __restrict__ locs,
                                               const float* __restrict__ priors,
                                               float* __restrict__ boxF,
                                               float* __restrict__ scoreF,
                                               int* __restrict__ validI) {
  const int b = blockIdx.x;
  __shared__ u64 A[KTOP];
  __shared__ u64 Bv[KTOP];
  const u64* src = keyG + (size_t)b * NPRI;
  for (int i = threadIdx.x; i < KTOP; i += 256) A[i] = src[i];
  for (int c = 1; c < NCH; c++) {
    __syncthreads();
    for (int i = threadIdx.x; i < KTOP; i += 256)
      Bv[i] = src[(size_t)c * KTOP + (KTOP - 1 - i)];   // reversed: asc
    __syncthreads();
    // half-cleaner: A(desc) ++ B(asc) bitonic -> elementwise max = top-1024 (bitonic)
    for (int i = threadIdx.x; i < KTOP; i += 256)
      if (Bv[i] > A[i]) A[i] = Bv[i];
    // clean -> descending
    for (int j = KTOP / 2; j > 0; j >>= 1) {
      __syncthreads();
      for (int l = threadIdx.x; l < KTOP; l += 256) {
        int p = l ^ j;
        if (p > l) {
          u64 a = A[l], q = A[p];
          if (a < q) { A[l] = q; A[p] = a; }
        }
      }
    }
  }
  __syncthreads();
  // f32-stepwise decode (identical expressions to round 7)
  for (int i = threadIdx.x; i < KTOP; i += 256) {
    u64 K = A[i];
    float sv = __uint_as_float((u32)(K >> 15));
    int idx = NPRI - 1 - (int)(K & 0x7FFFu);
    float4 lo = ((const float4*)locs)[(size_t)b * NPRI + idx];
    float4 pr = ((const float4*)priors)[idx];
    float cx = pr.x + (lo.x * 0.1f) * pr.z;
    float cy = pr.y + (lo.y * 0.1f) * pr.w;
    float w  = pr.z * crexpf(lo.z * 0.2f);
    float h  = pr.w * crexpf(lo.w * 0.2f);
    float x1 = cx - w * 0.5f;
    float y1 = cy - h * 0.5f;
    float x2 = x1 + w;
    float y2 = y1 + h;
    size_t o = (size_t)b * KTOP + i;
    boxF[o * 4 + 0] = x1;
    boxF[o * 4 + 1] = y1;
    boxF[o * 4 + 2] = x2;
    boxF[o * 4 + 3] = y2;
    scoreF[o] = sv;
    validI[o] = (sv > 0.5f) ? 1 : 0;
  }
}

// K3: suppression bitmask rows: bit j of row i = (iou(i,j) > 0.4f) && (j > i).
// Expression order identical to round 7's validated inner loop.
__global__ __launch_bounds__(256) void k_iou(const float* __restrict__ boxF,
                                             u64* __restrict__ sup) {
  const int b = blockIdx.y;
  const int i = blockIdx.x * 256 + threadIdx.x;
  __shared__ float X1[KTOP], Y1[KTOP], X2[KTOP], Y2[KTOP], AR[KTOP];
  const float* bb = boxF + (size_t)b * KTOP * 4;
  for (int l = threadIdx.x; l < KTOP; l += 256) {
    float x1 = bb[l * 4 + 0], y1 = bb[l * 4 + 1];
    float x2 = bb[l * 4 + 2], y2 = bb[l * 4 + 3];
    X1[l] = x1; Y1[l] = y1; X2[l] = x2; Y2[l] = y2;
    AR[l] = fmaxf(x2 - x1, 0.0f) * fmaxf(y2 - y1, 0.0f);
  }
  __syncthreads();
  const float x1 = X1[i], y1 = Y1[i], x2 = X2[i], y2 = Y2[i], a = AR[i];
  u64* row = sup + ((size_t)b * KTOP + i) * 16;
  for (int jw = 0; jw < 16; jw++) {
    u64 word = 0;
    const int jbase = jw * 64;
    for (int jb = 0; jb < 64; jb++) {
      int j = jbase + jb;
      float lx = fmaxf(x1, X1[j]);
      float ly = fmaxf(y1, Y1[j]);
      float rx = fminf(x2, X2[j]);
      float ry = fminf(y2, Y2[j]);
      float iw = fmaxf(rx - lx, 0.0f);
      float ih = fmaxf(ry - ly, 0.0f);
      float inter = iw * ih;
      float uni = (a + AR[j]) - inter;
      float iou = inter / fmaxf(uni, 1e-9f);
      if (iou > 0.4f && j > i) word |= (1ULL << jb);
    }
    row[jw] = word;
  }
}

// K4: greedy scan over the bitmask (wave 0: lane w<16 holds removal word w;
// round-1-validated state machine), then masked f32 output write.
__global__ __launch_bounds__(256) void k_scan(const u64* __restrict__ sup,
                                              const int* __restrict__ validI,
                                              const float* __restrict__ boxF,
                                              const float* __restrict__ scoreF,
                                              float* __restrict__ out) {
  const int b = blockIdx.x;
  __shared__ u64 rows[64][16];
  __shared__ unsigned char keepF[KTOP];
  __shared__ unsigned char vld[KTOP];
  for (int i = threadIdx.x; i < KTOP; i += 256)
    vld[i] = (unsigned char)validI[(size_t)b * KTOP + i];
  u64 remv = 0;
  const int lane = threadIdx.x;
  for (int g = 0; g < 16; g++) {
    __syncthreads();
    for (int l = threadIdx.x; l < 1024; l += 256)
      rows[l >> 4][l & 15] = sup[((size_t)b * KTOP + g * 64) * 16 + l];
    __syncthreads();
    if (threadIdx.x < 64) {
      for (int i2 = 0; i2 < 64; i2++) {
        u64 rg = __shfl(remv, g);
        bool rm = (rg >> i2) & 1ULL;
        bool cond = vld[g * 64 + i2] && !rm;
        if (cond && lane < 16) remv |= rows[i2][lane];
        if (lane == 0) keepF[g * 64 + i2] = cond ? 1 : 0;
      }
    }
  }
  __syncthreads();
  const float* bb = boxF + (size_t)b * KTOP * 4;
  const float* sc = scoreF + (size_t)b * KTOP;
  for (int i = threadIdx.x; i < KTOP; i += 256) {
    float kf = keepF[i] ? 1.0f : 0.0f;
    size_t o5 = ((size_t)b * KTOP + i) * 5;
    out[o5 + 0] = bb[i * 4 + 0] * kf;
    out[o5 + 1] = bb[i * 4 + 1] * kf;
    out[o5 + 2] = bb[i * 4 + 2] * kf;
    out[o5 + 3] = bb[i * 4 + 3] * kf;
    out[o5 + 4] = sc[i] * kf;
    out[(size_t)BATCH * KTOP * 5 + (size_t)b * KTOP + i] = kf;
  }
}

extern "C" void kernel_launch(void* const* d_in, const int* in_sizes, int n_in,
                              void* d_out, int out_size, void* d_ws, size_t ws_size,
                              hipStream_t stream) {
  const float* locs = nullptr;
  const float* confs = nullptr;
  const float* priors = nullptr;
  for (int i = 0; i < n_in; i++) {
    if (in_sizes[i] == BATCH * NPRI * 4) locs = (const float*)d_in[i];
    else if (in_sizes[i] == BATCH * NPRI * 2) confs = (const float*)d_in[i];
    else if (in_sizes[i] == NPRI * 4) priors = (const float*)d_in[i];
  }
  float* out = (float*)d_out;   // f32: [B,K,5] dets ++ [B,K] keep

  char* ws = (char*)d_ws;
  size_t off = 0;
  u64* keyG = (u64*)(ws + off);          // B*N*8 = 11,010,048 B
  u64* sup = (u64*)(ws + off);           // alias: keyG dead after k_merge (needs 8,388,608 B)
  off += (size_t)BATCH * NPRI * 8;
  float* boxF = (float*)(ws + off);      off += (size_t)BATCH * KTOP * 4 * 4;   // 1,048,576
  float* scoreF = (float*)(ws + off);    off += (size_t)BATCH * KTOP * 4;       //   262,144
  int* validI = (int*)(ws + off);        off += (size_t)BATCH * KTOP * 4;       //   262,144

  k_sort<<<BATCH * NCH, 256, 0, stream>>>(confs, keyG);
  k_merge<<<BATCH, 256, 0, stream>>>(keyG, locs, priors, boxF, scoreF, validI);
  k_iou<<<dim3(4, BATCH), 256, 0, stream>>>(boxF, sup);
  k_scan<<<BATCH, 256, 0, stream>>>(sup, validI, boxF, scoreF, out);
}

// Round 9
// 365.767 us; speedup vs baseline: 40.2727x; 1.3366x over previous
//
#include <hip/hip_runtime.h>

#define NPRI 21504
#define BATCH 64
#define KTOP 1024
#define NCH 21

typedef unsigned long long u64;
typedef unsigned int u32;

// correctly-rounded f32 exp via f64 libm exp (validated: absmax 3e-8)
__device__ __forceinline__ float crexpf(float x) { return (float)exp((double)x); }

// Key packing: score>0 so f32 bits are order-monotone. NPRI-1-idx < 2^15.
// Descending u64 order == (score desc, idx asc) == lax.top_k stable order.
// Keys are UNIQUE (idx embedded) => top-1024 multiset + desc order is unique,
// so any correct selection structure is bit-exact.

// K1: fused f32-stepwise softmax score + per-chunk bitonic sort (desc) of u64 keys.
__global__ __launch_bounds__(256) void k_sort(const float* __restrict__ confs,
                                              u64* __restrict__ keyG) {
  const int b = blockIdx.x / NCH;
  const int c = blockIdx.x % NCH;
  __shared__ u64 ks[KTOP];
  const float2* cf = (const float2*)confs + (size_t)b * NPRI + c * KTOP;
  for (int i = threadIdx.x; i < KTOP; i += 256) {
    float2 v = cf[i];
    float m = fmaxf(v.x, v.y);
    float e0 = crexpf(v.x - m);
    float e1 = crexpf(v.y - m);
    float s = e1 / (e0 + e1);          // exact f32 steps (validated)
    int idx = c * KTOP + i;
    ks[i] = ((u64)__float_as_uint(s) << 15) | (u64)(NPRI - 1 - idx);
  }
  for (int k = 2; k <= KTOP; k <<= 1) {
    for (int j = k >> 1; j > 0; j >>= 1) {
      __syncthreads();
      for (int l = threadIdx.x; l < KTOP; l += 256) {
        int p = l ^ j;
        if (p > l) {
          u64 a = ks[l], q = ks[p];
          bool up = ((l & k) == 0);
          if ((a > q) != up) { ks[l] = q; ks[p] = a; }
        }
      }
    }
  }
  __syncthreads();
  u64* dst = keyG + (size_t)b * NPRI + (size_t)c * KTOP;
  for (int i = threadIdx.x; i < KTOP; i += 256) dst[i] = ks[i];
}

// K2 (xN levels): pairwise top-1024 merge of sorted runs. When nIn is odd, the
// last run is copied. finalDecode=1 on the last level: decode + valid-ballot.
__global__ __launch_bounds__(256) void k_mergeL(const u64* __restrict__ src,
                                                u64* __restrict__ dst, int nIn,
                                                const float* __restrict__ locs,
                                                const float* __restrict__ priors,
                                                float* __restrict__ boxF,
                                                float* __restrict__ scoreF,
                                                u64* __restrict__ validW,
                                                int finalDecode) {
  const int nOut = (nIn + 1) >> 1;
  const int b = blockIdx.x / nOut;
  const int m = blockIdx.x % nOut;
  const u64* sA = src + ((size_t)b * nIn + 2 * m) * KTOP;
  u64* d = dst + ((size_t)b * nOut + m) * KTOP;
  __shared__ u64 A[KTOP];
  if (2 * m + 1 < nIn) {
    const u64* sB = sA + KTOP;
    // half-cleaner: A[i] vs reversed B -> elementwise max = bitonic top-1024
    for (int i = threadIdx.x; i < KTOP; i += 256) {
      u64 a = sA[i];
      u64 q = sB[KTOP - 1 - i];
      A[i] = a > q ? a : q;
    }
    // clean -> descending
    for (int j = KTOP / 2; j > 0; j >>= 1) {
      __syncthreads();
      for (int l = threadIdx.x; l < KTOP; l += 256) {
        int p = l ^ j;
        if (p > l) {
          u64 a = A[l], q = A[p];
          if (a < q) { A[l] = q; A[p] = a; }
        }
      }
    }
    __syncthreads();
    if (!finalDecode)
      for (int i = threadIdx.x; i < KTOP; i += 256) d[i] = A[i];
  } else {
    for (int i = threadIdx.x; i < KTOP; i += 256) d[i] = sA[i];
  }
  if (finalDecode) {
    // f32-stepwise decode (identical expressions to validated round 7)
    for (int i = threadIdx.x; i < KTOP; i += 256) {
      u64 K = A[i];
      float sv = __uint_as_float((u32)(K >> 15));
      int idx = NPRI - 1 - (int)(K & 0x7FFFu);
      float4 lo = ((const float4*)locs)[(size_t)b * NPRI + idx];
      float4 pr = ((const float4*)priors)[idx];
      float cx = pr.x + (lo.x * 0.1f) * pr.z;
      float cy = pr.y + (lo.y * 0.1f) * pr.w;
      float w  = pr.z * crexpf(lo.z * 0.2f);
      float h  = pr.w * crexpf(lo.w * 0.2f);
      float x1 = cx - w * 0.5f;
      float y1 = cy - h * 0.5f;
      float x2 = x1 + w;
      float y2 = y1 + h;
      size_t o = (size_t)b * KTOP + i;
      boxF[o * 4 + 0] = x1;
      boxF[o * 4 + 1] = y1;
      boxF[o * 4 + 2] = x2;
      boxF[o * 4 + 3] = y2;
      scoreF[o] = sv;
      u64 mask = __ballot(sv > 0.5f);       // wave covers group i>>6
      if ((threadIdx.x & 63) == 0) validW[(size_t)b * 16 + (i >> 6)] = mask;
    }
  }
}

// K3: suppression bitmask rows (validated expressions, f32).
__global__ __launch_bounds__(256) void k_iou(const float* __restrict__ boxF,
                                             u64* __restrict__ sup) {
  const int b = blockIdx.y;
  const int i = blockIdx.x * 256 + threadIdx.x;
  __shared__ float X1[KTOP], Y1[KTOP], X2[KTOP], Y2[KTOP], AR[KTOP];
  const float* bb = boxF + (size_t)b * KTOP * 4;
  for (int l = threadIdx.x; l < KTOP; l += 256) {
    float x1 = bb[l * 4 + 0], y1 = bb[l * 4 + 1];
    float x2 = bb[l * 4 + 2], y2 = bb[l * 4 + 3];
    X1[l] = x1; Y1[l] = y1; X2[l] = x2; Y2[l] = y2;
    AR[l] = fmaxf(x2 - x1, 0.0f) * fmaxf(y2 - y1, 0.0f);
  }
  __syncthreads();
  const float x1 = X1[i], y1 = Y1[i], x2 = X2[i], y2 = Y2[i], a = AR[i];
  u64* row = sup + ((size_t)b * KTOP + i) * 16;
  for (int jw = 0; jw < 16; jw++) {
    u64 word = 0;
    const int jbase = jw * 64;
    for (int jb = 0; jb < 64; jb++) {
      int j = jbase + jb;
      float lx = fmaxf(x1, X1[j]);
      float ly = fmaxf(y1, Y1[j]);
      float rx = fminf(x2, X2[j]);
      float ry = fminf(y2, Y2[j]);
      float iw = fmaxf(rx - lx, 0.0f);
      float ih = fmaxf(ry - ly, 0.0f);
      float inter = iw * ih;
      float uni = (a + AR[j]) - inter;
      float iou = inter / fmaxf(uni, 1e-9f);
      if (iou > 0.4f && j > i) word |= (1ULL << jb);
    }
    row[jw] = word;
  }
}

// K4: group-synchronous greedy NMS. Per 64-group: wave-0 serial alive-mask
// recurrence (wave-uniform => scalar-branch skip of dead lanes), then all 256
// threads OR kept rows into future removal words. Exact greedy semantics.
__global__ __launch_bounds__(256) void k_scan(const u64* __restrict__ sup,
                                              const u64* __restrict__ validW,
                                              const float* __restrict__ boxF,
                                              const float* __restrict__ scoreF,
                                              float* __restrict__ out) {
  const int b = blockIdx.x;
  const int t = threadIdx.x;
  __shared__ u64 rows[64][16];
  __shared__ u64 remv[16];
  __shared__ u64 keepW[16];
  __shared__ u64 vW[16];
  if (t < 16) { remv[t] = 0; vW[t] = validW[(size_t)b * 16 + t]; }
  __syncthreads();
  for (int g = 0; g < 16; g++) {
    // load this group's 64 rows (8 KB, coalesced)
    for (int l = t; l < 1024; l += 256)
      rows[l >> 4][l & 15] = sup[((size_t)b * KTOP + g * 64) * 16 + l];
    __syncthreads();
    if (t < 64) {
      u64 diag = rows[t][g];                // lane i: row i's intra-group word
      u64 alive = vW[g] & ~remv[g];         // wave-uniform
      for (int i = 0; i < 64; i++) {
        if ((alive >> i) & 1ULL)            // uniform -> scalar branch
          alive &= ~__shfl(diag, i);        // row i only has bits j>i
      }
      if (t == 0) keepW[g] = alive;
    }
    __syncthreads();
    // OR kept rows into removal words of future groups
    {
      u64 kw = keepW[g];
      int w = t & 15;
      if (w > g) {
        int i0 = (t >> 4) * 4;
        u64 acc = 0;
        for (int i = i0; i < i0 + 4; i++)
          if ((kw >> i) & 1ULL) acc |= rows[i][w];
        if (acc) atomicOr(&remv[w], acc);
      }
    }
    __syncthreads();   // remv visible; rows reusable
  }
  const float* bb = boxF + (size_t)b * KTOP * 4;
  const float* sc = scoreF + (size_t)b * KTOP;
  for (int i = t; i < KTOP; i += 256) {
    float kf = ((keepW[i >> 6] >> (i & 63)) & 1ULL) ? 1.0f : 0.0f;
    size_t o5 = ((size_t)b * KTOP + i) * 5;
    out[o5 + 0] = bb[i * 4 + 0] * kf;
    out[o5 + 1] = bb[i * 4 + 1] * kf;
    out[o5 + 2] = bb[i * 4 + 2] * kf;
    out[o5 + 3] = bb[i * 4 + 3] * kf;
    out[o5 + 4] = sc[i] * kf;
    out[(size_t)BATCH * KTOP * 5 + (size_t)b * KTOP + i] = kf;
  }
}

extern "C" void kernel_launch(void* const* d_in, const int* in_sizes, int n_in,
                              void* d_out, int out_size, void* d_ws, size_t ws_size,
                              hipStream_t stream) {
  const float* locs = nullptr;
  const float* confs = nullptr;
  const float* priors = nullptr;
  for (int i = 0; i < n_in; i++) {
    if (in_sizes[i] == BATCH * NPRI * 4) locs = (const float*)d_in[i];
    else if (in_sizes[i] == BATCH * NPRI * 2) confs = (const float*)d_in[i];
    else if (in_sizes[i] == NPRI * 4) priors = (const float*)d_in[i];
  }
  float* out = (float*)d_out;   // f32: [B,K,5] dets ++ [B,K] keep

  char* ws = (char*)d_ws;
  size_t off = 0;
  u64* keyG = (u64*)(ws + off);          // B*N*8 = 11,010,048
  u64* sup = (u64*)(ws + off);           // alias: keyG dead after last merge (8,388,608)
  off += (size_t)BATCH * NPRI * 8;
  u64* bufB = (u64*)(ws + off);          off += (size_t)BATCH * 11 * KTOP * 8;  // 5,767,168
  float* boxF = (float*)(ws + off);      off += (size_t)BATCH * KTOP * 4 * 4;   // 1,048,576
  float* scoreF = (float*)(ws + off);    off += (size_t)BATCH * KTOP * 4;       //   262,144
  u64* validW = (u64*)(ws + off);        off += (size_t)BATCH * 16 * 8;         //     8,192
  // total ~18.1 MB

  k_sort<<<BATCH * NCH, 256, 0, stream>>>(confs, keyG);
  // tree merge: 21 -> 11 -> 6 -> 3 -> 2 -> 1
  k_mergeL<<<BATCH * 11, 256, 0, stream>>>(keyG, bufB, 21, locs, priors, boxF, scoreF, validW, 0);
  k_mergeL<<<BATCH * 6, 256, 0, stream>>>(bufB, keyG, 11, locs, priors, boxF, scoreF, validW, 0);
  k_mergeL<<<BATCH * 3, 256, 0, stream>>>(keyG, bufB, 6, locs, priors, boxF, scoreF, validW, 0);
  k_mergeL<<<BATCH * 2, 256, 0, stream>>>(bufB, keyG, 3, locs, priors, boxF, scoreF, validW, 0);
  k_mergeL<<<BATCH * 1, 256, 0, stream>>>(keyG, bufB, 2, locs, priors, boxF, scoreF, validW, 1);
  k_iou<<<dim3(4, BATCH), 256, 0, stream>>>(boxF, sup);
  k_scan<<<BATCH, 256, 0, stream>>>(sup, validW, boxF, scoreF, out);
}